// Round 14
// baseline (166.786 us; speedup 1.0000x reference)
//
#include <hip/hip_runtime.h>
#include <hip/hip_bf16.h>

#define BB 2
#define SS 2048
#define HH 16
#define DD 64

#define LOG2E 1.4426950408889634f

typedef __bf16 bf16x8 __attribute__((ext_vector_type(8)));
typedef float f32x4 __attribute__((ext_vector_type(4)));
typedef float f32x16 __attribute__((ext_vector_type(16)));

__device__ __forceinline__ void gld16(const __hip_bfloat16* g, __hip_bfloat16* l) {
    __builtin_amdgcn_global_load_lds(
        (const __attribute__((address_space(1))) unsigned int*)g,
        (__attribute__((address_space(3))) unsigned int*)l, 16, 0, 0);
}

// ---------------------------------------------------------------------------
// Kernel 1: fused Q/K/V projection + V transpose + Q pre-scaling. (unchanged)
// ---------------------------------------------------------------------------
__global__ __launch_bounds__(256) void proj_kernel(
    const float* __restrict__ xq, const float* __restrict__ xk,
    const float* __restrict__ xv,
    const float* __restrict__ Wq, const float* __restrict__ bq,
    const float* __restrict__ Wk, const float* __restrict__ bk,
    const float* __restrict__ Wv, const float* __restrict__ bv,
    const float* __restrict__ inv_scale_p,
    __hip_bfloat16* __restrict__ Qp, __hip_bfloat16* __restrict__ Kp,
    __hip_bfloat16* __restrict__ Vt)
{
    __shared__ float w_lds[64][65];
    __shared__ __attribute__((aligned(16))) float x_lds[64][72];
    __shared__ __attribute__((aligned(16))) __hip_bfloat16 vt_lds[64][72];

    const int tid = threadIdx.x;
    const int bh = blockIdx.x;
    const int b = bh >> 4, h = bh & 15;
    const int s0 = blockIdx.y * 64;
    const int e = tid & 63;
    const int rg = tid >> 6;
    const float qscale = LOG2E / inv_scale_p[0];

    const float* xs[3] = {xq, xk, xv};
    const float* Ws[3] = {Wq, Wk, Wv};
    const float* Bs[3] = {bq, bk, bv};

#pragma unroll
    for (int m = 0; m < 3; ++m) {
        __syncthreads();
#pragma unroll
        for (int k = 0; k < 16; ++k) {
            const int i = tid + k * 256;
            w_lds[i & 63][i >> 6] = Ws[m][i];
        }
        {
            const int row = tid >> 2, f0 = tid & 3;
            const float* xrow = xs[m] + ((size_t)((b * SS + s0 + row) * HH + h)) * DD;
            float4* dst = (float4*)&x_lds[row][0];
            const float4* src = (const float4*)xrow;
#pragma unroll
            for (int j = 0; j < 4; ++j) dst[f0 + 4 * j] = src[f0 + 4 * j];
        }
        const float bias_e = Bs[m][e];
        __syncthreads();

        float acc[16];
#pragma unroll
        for (int it = 0; it < 16; ++it) acc[it] = bias_e;
#pragma unroll
        for (int dq = 0; dq < 16; ++dq) {
            const float w0 = w_lds[dq * 4 + 0][e];
            const float w1 = w_lds[dq * 4 + 1][e];
            const float w2 = w_lds[dq * 4 + 2][e];
            const float w3 = w_lds[dq * 4 + 3][e];
#pragma unroll
            for (int it = 0; it < 16; ++it) {
                const float4 x4 = *(const float4*)&x_lds[rg * 16 + it][dq * 4];
                acc[it] = fmaf(x4.x, w0, fmaf(x4.y, w1, fmaf(x4.z, w2, fmaf(x4.w, w3, acc[it]))));
            }
        }

        if (m == 0) {
#pragma unroll
            for (int it = 0; it < 16; ++it)
                Qp[((size_t)bh * SS + s0 + rg * 16 + it) * DD + e] =
                    __float2bfloat16(acc[it] * qscale);
        } else if (m == 1) {
#pragma unroll
            for (int it = 0; it < 16; ++it)
                Kp[((size_t)bh * SS + s0 + rg * 16 + it) * DD + e] =
                    __float2bfloat16(acc[it]);
        } else {
#pragma unroll
            for (int it = 0; it < 16; ++it)
                vt_lds[e][rg * 16 + it] = __float2bfloat16(acc[it]);
            __syncthreads();
            const int row2 = tid >> 2, f = tid & 3;
            bf16x8 vv0 = *(const bf16x8*)&vt_lds[row2][f * 16];
            bf16x8 vv1 = *(const bf16x8*)&vt_lds[row2][f * 16 + 8];
            __hip_bfloat16* dst = &Vt[((size_t)bh * DD + row2) * SS + s0 + f * 16];
            *(bf16x8*)dst = vv0;
            *(bf16x8*)(dst + 8) = vv1;
        }
    }
}

// ---------------------------------------------------------------------------
// Kernel 2: flash attention, software-pipelined across tiles:
// per body: {STAGE(t+2) | QK(t+1) | softmax+PV(t)} + 1 barrier.
// Triple-buffered LDS (48 KB), score ping-pong sA/sB, mask regs 2 ahead.
// 32x32x16 MFMA, 32 q-rows/wave, QBLK=128, K/V-sharing XCD remap.
// grid = 512 (2 blocks/CU); block = 256 (4 waves).
// ---------------------------------------------------------------------------
__global__ __launch_bounds__(256, 2) void attn_kernel(
    const __hip_bfloat16* __restrict__ Qp, const __hip_bfloat16* __restrict__ Kp,
    const __hip_bfloat16* __restrict__ Vt, const float* __restrict__ mask,
    float* __restrict__ out)
{
    __shared__ __attribute__((aligned(16))) __hip_bfloat16 Kl[3][4096];
    __shared__ __attribute__((aligned(16))) __hip_bfloat16 Vl[3][4096];

    const int tid = threadIdx.x;
    const int lane = tid & 63;
    const int wave = tid >> 6;
    const int ln31 = lane & 31;
    const int hi = lane >> 5;

    // K/V-sharing XCD remap (bijective on [0,512))
    const int hw = blockIdx.x;
    const int bh = ((hw >> 7) << 3) + (hw & 7);
    const int qt = (hw & 127) >> 3;
    const int b = bh >> 4;

    const __hip_bfloat16* Qb = Qp + (size_t)bh * SS * DD;
    const __hip_bfloat16* Kb = Kp + (size_t)bh * SS * DD;
    const __hip_bfloat16* Vtb = Vt + (size_t)bh * DD * SS;

    const int q0 = qt * 128 + wave * 32;
    const float* mq = mask + (size_t)b * SS * SS + (size_t)(q0 + ln31) * SS;

    const int srow = lane >> 3;
    const int scol = ((lane & 7) ^ srow) * 8;
    const int rswz = (lane & 7) << 4;

    bf16x8 qf[4];
    {
        const __hip_bfloat16* qptr = Qb + (size_t)(q0 + ln31) * DD + hi * 8;
#pragma unroll
        for (int kc = 0; kc < 4; ++kc)
            qf[kc] = *reinterpret_cast<const bf16x8*>(qptr + kc * 16);
    }

    bf16x8 ones;
#pragma unroll
    for (int i = 0; i < 8; ++i) ones[i] = (__bf16)1.0f;

    f32x16 o[2];
    f32x16 lacc;
    float m_r = -1e30f;
#pragma unroll
    for (int r = 0; r < 16; ++r) { o[0][r] = 0.f; o[1][r] = 0.f; lacc[r] = 0.f; }

    f32x16 sA[2], sB[2];
    f32x4 mvA[2][4], mvB[2][4];
    int b0 = 0, b1 = 1, b2 = 2;

#define STAGE(bi, t0s)                                                          \
    {                                                                           \
        _Pragma("unroll")                                                       \
        for (int cc = 0; cc < 2; ++cc) {                                        \
            const int c = wave * 2 + cc;                                        \
            const int row = c * 8 + srow;                                       \
            gld16(Kb + (size_t)((t0s) + row) * DD + scol,                       \
                  (__hip_bfloat16*)((char*)Kl + (bi) * 8192) + c * 512);        \
            gld16(Vtb + (size_t)row * SS + (t0s) + scol,                        \
                  (__hip_bfloat16*)((char*)Vl + (bi) * 8192) + c * 512);        \
        }                                                                       \
    }

#define LOADMASK(mv, t0s)                                                       \
    {                                                                           \
        _Pragma("unroll")                                                       \
        for (int nt = 0; nt < 2; ++nt)                                          \
            _Pragma("unroll")                                                   \
            for (int gi = 0; gi < 4; ++gi)                                      \
                mv[nt][gi] = *(const f32x4*)&mq[(t0s) + nt * 32 + hi * 4 + gi * 8]; \
    }

#define KFRAG(bi, nt, kc) (*(const bf16x8*)((const char*)Kl + (bi) * 8192 +     \
        (nt) * 4096 + ln31 * 128 + (((kc) * 32 + hi * 16) ^ rswz)))
#define VFRAG(bi, nt, kc) (*(const bf16x8*)((const char*)Vl + (bi) * 8192 +     \
        (nt) * 4096 + ln31 * 128 + (((kc) * 32 + hi * 16) ^ rswz)))

// QK for tile at offset tQK from buffer bi, C-init from MVQ, into SNXT
#define QKSTEP(SNXT, MVQ, bi)                                                   \
    {                                                                           \
        _Pragma("unroll")                                                       \
        for (int nt = 0; nt < 2; ++nt)                                          \
            _Pragma("unroll")                                                   \
            for (int r = 0; r < 16; ++r)                                        \
                SNXT[nt][r] = MVQ[nt][r >> 2][r & 3] * LOG2E;                   \
        __builtin_amdgcn_s_setprio(1);                                          \
        _Pragma("unroll")                                                       \
        for (int kc = 0; kc < 4; ++kc) {                                        \
            bf16x8 k0 = KFRAG(bi, 0, kc);                                       \
            bf16x8 k1 = KFRAG(bi, 1, kc);                                       \
            SNXT[0] = __builtin_amdgcn_mfma_f32_32x32x16_bf16(k0, qf[kc], SNXT[0], 0, 0, 0); \
            SNXT[1] = __builtin_amdgcn_mfma_f32_32x32x16_bf16(k1, qf[kc], SNXT[1], 0, 0, 0); \
        }                                                                       \
        __builtin_amdgcn_s_setprio(0);                                          \
    }

// softmax + PV of the tile whose scores are in SCUR, V from buffer b0
#define SOFTPV(SCUR)                                                            \
    {                                                                           \
        bf16x8 vfr0[4], vfr1[4];                                                \
        _Pragma("unroll")                                                       \
        for (int kc = 0; kc < 4; ++kc) {                                        \
            vfr0[kc] = VFRAG(b0, 0, kc);                                        \
            vfr1[kc] = VFRAG(b0, 1, kc);                                        \
        }                                                                       \
        float pmax = fmaxf(SCUR[0][0], fmaxf(SCUR[0][1], SCUR[0][2]));          \
        _Pragma("unroll")                                                       \
        for (int r = 3; r < 16; r += 3)                                         \
            pmax = fmaxf(pmax, fmaxf(SCUR[0][r],                                \
                fmaxf(SCUR[0][(r + 1) & 15], SCUR[0][(r + 2) & 15])));          \
        _Pragma("unroll")                                                       \
        for (int r = 0; r < 16; r += 4)                                         \
            pmax = fmaxf(pmax, fmaxf(fmaxf(SCUR[1][r], SCUR[1][r + 1]),         \
                fmaxf(SCUR[1][r + 2], SCUR[1][r + 3])));                        \
        if (!__all(pmax - m_r <= 11.5f)) {                                      \
            float mx = fmaxf(pmax, __shfl_xor(pmax, 32));                       \
            const float mn = fmaxf(m_r, mx);                                    \
            const float alpha = exp2f(m_r - mn);                                \
            m_r = mn;                                                           \
            _Pragma("unroll")                                                   \
            for (int r = 0; r < 16; ++r) {                                      \
                const float a = __shfl(alpha, (r & 3) + 8 * (r >> 2) + 4 * hi); \
                o[0][r] *= a; o[1][r] *= a; lacc[r] *= a;                       \
            }                                                                   \
        }                                                                       \
        _Pragma("unroll")                                                       \
        for (int nt = 0; nt < 2; ++nt)                                          \
            _Pragma("unroll")                                                   \
            for (int r = 0; r < 16; ++r)                                        \
                SCUR[nt][r] = __builtin_amdgcn_exp2f(SCUR[nt][r] - m_r);        \
        bf16x8 pfa[4];                                                          \
        _Pragma("unroll")                                                       \
        for (int nt = 0; nt < 2; ++nt) {                                        \
            unsigned cw[8];                                                     \
            _Pragma("unroll")                                                   \
            for (int j = 0; j < 8; ++j) {                                       \
                union { __hip_bfloat162 hh; unsigned u; } cu;                   \
                cu.hh = __float22bfloat162_rn(                                  \
                    make_float2(SCUR[nt][2 * j], SCUR[nt][2 * j + 1]));         \
                cw[j] = cu.u;                                                   \
            }                                                                   \
            _Pragma("unroll")                                                   \
            for (int half = 0; half < 2; ++half) {                              \
                const unsigned c0 = cw[half * 4 + 0], c1 = cw[half * 4 + 1];    \
                const unsigned c2 = cw[half * 4 + 2], c3 = cw[half * 4 + 3];    \
                const unsigned X  = hi ? c0 : c2;                               \
                const unsigned Y  = (unsigned)__shfl_xor((int)X, 32);           \
                const unsigned X2 = hi ? c1 : c3;                               \
                const unsigned Y2 = (unsigned)__shfl_xor((int)X2, 32);          \
                union { bf16x8 v; unsigned w[4]; } pu;                          \
                pu.w[0] = hi ? Y : c0;                                          \
                pu.w[1] = hi ? Y2 : c1;                                         \
                pu.w[2] = hi ? c2 : Y;                                          \
                pu.w[3] = hi ? c3 : Y2;                                         \
                pfa[nt * 2 + half] = pu.v;                                      \
            }                                                                   \
        }                                                                       \
        __builtin_amdgcn_s_setprio(1);                                          \
        _Pragma("unroll")                                                       \
        for (int kc = 0; kc < 4; ++kc) {                                        \
            lacc = __builtin_amdgcn_mfma_f32_32x32x16_bf16(pfa[kc], ones, lacc, 0, 0, 0); \
            o[0] = __builtin_amdgcn_mfma_f32_32x32x16_bf16(pfa[kc], vfr0[kc], o[0], 0, 0, 0); \
            o[1] = __builtin_amdgcn_mfma_f32_32x32x16_bf16(pfa[kc], vfr1[kc], o[1], 0, 0, 0); \
        }                                                                       \
        __builtin_amdgcn_s_setprio(0);                                          \
    }

// full pipelined body: PV tile tPV, QK tile tPV+64, stage tile tPV+128
#define BODY(SCUR, SNXT, MVQ, tPV)                                              \
    {                                                                           \
        if ((tPV) + 128 < SS) STAGE(b2, (tPV) + 128);                           \
        QKSTEP(SNXT, MVQ, b1);                                                  \
        if ((tPV) + 192 < SS) LOADMASK(MVQ, (tPV) + 192);                       \
        SOFTPV(SCUR);                                                           \
        __syncthreads();                                                        \
        { const int _t = b0; b0 = b1; b1 = b2; b2 = _t; }                       \
    }

    // ---- prologue: stage tiles 0,1; masks for tiles 0,1; QK(0) ----
    STAGE(b0, 0);
    STAGE(b1, 64);
    LOADMASK(mvB, 0);
    LOADMASK(mvA, 64);
    __syncthreads();
    QKSTEP(sA, mvB, b0);
    LOADMASK(mvB, 128);

    // ---- main pipelined loop: PV tiles 0..29 ----
#pragma unroll 1
    for (int i = 0; i < 15; ++i) {
        const int t = i * 128;
        BODY(sA, sB, mvA, t);
        BODY(sB, sA, mvB, t + 64);
    }

    // ---- epilogue: PV tile 30 (+QK tile 31), then PV tile 31 ----
    BODY(sA, sB, mvA, 1920);
    SOFTPV(sB);

    // ---- normalize and store ----
#pragma unroll
    for (int r = 0; r < 16; ++r) {
        const float inv_l = 1.0f / lacc[r];
        const int q = q0 + (r & 3) + 8 * (r >> 2) + 4 * hi;
        float* orow = out + ((size_t)bh * SS + q) * DD + ln31;
        orow[0]  = o[0][r] * inv_l;
        orow[32] = o[1][r] * inv_l;
    }
#undef STAGE
#undef LOADMASK
#undef KFRAG
#undef VFRAG
#undef QKSTEP
#undef SOFTPV
#undef BODY
}

extern "C" void kernel_launch(void* const* d_in, const int* in_sizes, int n_in,
                              void* d_out, int out_size, void* d_ws, size_t ws_size,
                              hipStream_t stream) {
    const float* xq        = (const float*)d_in[0];
    const float* xk        = (const float*)d_in[1];
    const float* xv        = (const float*)d_in[2];
    const float* mask      = (const float*)d_in[3];
    const float* inv_scale = (const float*)d_in[4];
    const float* Wq        = (const float*)d_in[5];
    const float* bq        = (const float*)d_in[6];
    const float* Wk        = (const float*)d_in[7];
    const float* bk        = (const float*)d_in[8];
    const float* Wv        = (const float*)d_in[9];
    const float* bv        = (const float*)d_in[10];

    __hip_bfloat16* Qp = (__hip_bfloat16*)d_ws;
    __hip_bfloat16* Kp = Qp + (size_t)BB * HH * SS * DD;
    __hip_bfloat16* Vt = Kp + (size_t)BB * HH * SS * DD;
    float* out = (float*)d_out;

    proj_kernel<<<dim3(BB * HH, SS / 64), dim3(256), 0, stream>>>(
        xq, xk, xv, Wq, bq, Wk, bk, Wv, bv, inv_scale, Qp, Kp, Vt);

    attn_kernel<<<dim3(512), dim3(256), 0, stream>>>(
        Qp, Kp, Vt, mask, out);
}

// Round 15
// 140.031 us; speedup vs baseline: 1.1911x; 1.1911x over previous
//
#include <hip/hip_runtime.h>
#include <hip/hip_bf16.h>

#define BB 2
#define SS 2048
#define HH 16
#define DD 64

#define LOG2E 1.4426950408889634f

typedef __bf16 bf16x8 __attribute__((ext_vector_type(8)));
typedef float f32x4 __attribute__((ext_vector_type(4)));
typedef float f32x16 __attribute__((ext_vector_type(16)));

__device__ __forceinline__ void gld16(const __hip_bfloat16* g, __hip_bfloat16* l) {
    __builtin_amdgcn_global_load_lds(
        (const __attribute__((address_space(1))) unsigned int*)g,
        (__attribute__((address_space(3))) unsigned int*)l, 16, 0, 0);
}

// ---------------------------------------------------------------------------
// Kernel 1: fused Q/K/V projection + V transpose + Q pre-scaling. (unchanged)
// ---------------------------------------------------------------------------
__global__ __launch_bounds__(256) void proj_kernel(
    const float* __restrict__ xq, const float* __restrict__ xk,
    const float* __restrict__ xv,
    const float* __restrict__ Wq, const float* __restrict__ bq,
    const float* __restrict__ Wk, const float* __restrict__ bk,
    const float* __restrict__ Wv, const float* __restrict__ bv,
    const float* __restrict__ inv_scale_p,
    __hip_bfloat16* __restrict__ Qp, __hip_bfloat16* __restrict__ Kp,
    __hip_bfloat16* __restrict__ Vt)
{
    __shared__ float w_lds[64][65];
    __shared__ __attribute__((aligned(16))) float x_lds[64][72];
    __shared__ __attribute__((aligned(16))) __hip_bfloat16 vt_lds[64][72];

    const int tid = threadIdx.x;
    const int bh = blockIdx.x;
    const int b = bh >> 4, h = bh & 15;
    const int s0 = blockIdx.y * 64;
    const int e = tid & 63;
    const int rg = tid >> 6;
    const float qscale = LOG2E / inv_scale_p[0];

    const float* xs[3] = {xq, xk, xv};
    const float* Ws[3] = {Wq, Wk, Wv};
    const float* Bs[3] = {bq, bk, bv};

#pragma unroll
    for (int m = 0; m < 3; ++m) {
        __syncthreads();
#pragma unroll
        for (int k = 0; k < 16; ++k) {
            const int i = tid + k * 256;
            w_lds[i & 63][i >> 6] = Ws[m][i];
        }
        {
            const int row = tid >> 2, f0 = tid & 3;
            const float* xrow = xs[m] + ((size_t)((b * SS + s0 + row) * HH + h)) * DD;
            float4* dst = (float4*)&x_lds[row][0];
            const float4* src = (const float4*)xrow;
#pragma unroll
            for (int j = 0; j < 4; ++j) dst[f0 + 4 * j] = src[f0 + 4 * j];
        }
        const float bias_e = Bs[m][e];
        __syncthreads();

        float acc[16];
#pragma unroll
        for (int it = 0; it < 16; ++it) acc[it] = bias_e;
#pragma unroll
        for (int dq = 0; dq < 16; ++dq) {
            const float w0 = w_lds[dq * 4 + 0][e];
            const float w1 = w_lds[dq * 4 + 1][e];
            const float w2 = w_lds[dq * 4 + 2][e];
            const float w3 = w_lds[dq * 4 + 3][e];
#pragma unroll
            for (int it = 0; it < 16; ++it) {
                const float4 x4 = *(const float4*)&x_lds[rg * 16 + it][dq * 4];
                acc[it] = fmaf(x4.x, w0, fmaf(x4.y, w1, fmaf(x4.z, w2, fmaf(x4.w, w3, acc[it]))));
            }
        }

        if (m == 0) {
#pragma unroll
            for (int it = 0; it < 16; ++it)
                Qp[((size_t)bh * SS + s0 + rg * 16 + it) * DD + e] =
                    __float2bfloat16(acc[it] * qscale);
        } else if (m == 1) {
#pragma unroll
            for (int it = 0; it < 16; ++it)
                Kp[((size_t)bh * SS + s0 + rg * 16 + it) * DD + e] =
                    __float2bfloat16(acc[it]);
        } else {
#pragma unroll
            for (int it = 0; it < 16; ++it)
                vt_lds[e][rg * 16 + it] = __float2bfloat16(acc[it]);
            __syncthreads();
            const int row2 = tid >> 2, f = tid & 3;
            bf16x8 vv0 = *(const bf16x8*)&vt_lds[row2][f * 16];
            bf16x8 vv1 = *(const bf16x8*)&vt_lds[row2][f * 16 + 8];
            __hip_bfloat16* dst = &Vt[((size_t)bh * DD + row2) * SS + s0 + f * 16];
            *(bf16x8*)dst = vv0;
            *(bf16x8*)(dst + 8) = vv1;
        }
    }
}

// ---------------------------------------------------------------------------
// Kernel 1b: mask transpose + log2e premul + bf16 narrowing.
//   maskT[b][t][q] = bf16(mask[b][q][t] * LOG2E)
// Makes the attn C-init load coalesced (lanes = consecutive q).
// grid = BB*32*32 (64x64 tiles); block = 256.
// ---------------------------------------------------------------------------
__global__ __launch_bounds__(256) void maskt_kernel(
    const float* __restrict__ mask, __hip_bfloat16* __restrict__ mt)
{
    __shared__ float tl[64][65];
    const int bid = blockIdx.x;
    const int b = bid >> 10;            // 1024 tiles per batch (32 x 32)
    const int q64 = (bid >> 5) & 31;
    const int t64 = bid & 31;
    const int tid = threadIdx.x;
    const int r0 = tid >> 4;            // 0..15
    const int c0 = (tid & 15) * 4;      // 0..60

    const float* src = mask + (size_t)b * SS * SS + (size_t)(q64 * 64) * SS + t64 * 64;
#pragma unroll
    for (int p = 0; p < 4; ++p) {
        const int r = p * 16 + r0;      // q-row within tile
        const float4 v = *(const float4*)&src[(size_t)r * SS + c0];
        tl[r][c0 + 0] = v.x; tl[r][c0 + 1] = v.y;
        tl[r][c0 + 2] = v.z; tl[r][c0 + 3] = v.w;
    }
    __syncthreads();

    __hip_bfloat16* dst = mt + (size_t)b * SS * SS + (size_t)(t64 * 64) * SS + q64 * 64;
#pragma unroll
    for (int p = 0; p < 4; ++p) {
        const int tt = p * 16 + r0;     // t-row within tile
        union { ushort4 u4; __hip_bfloat16 h[4]; } w;
        w.h[0] = __float2bfloat16(tl[c0 + 0][tt] * LOG2E);
        w.h[1] = __float2bfloat16(tl[c0 + 1][tt] * LOG2E);
        w.h[2] = __float2bfloat16(tl[c0 + 2][tt] * LOG2E);
        w.h[3] = __float2bfloat16(tl[c0 + 3][tt] * LOG2E);
        *(ushort4*)&dst[(size_t)tt * SS + c0] = w.u4;
    }
}

// ---------------------------------------------------------------------------
// Kernel 2: flash attention (R13 structure).  Mask C-init now from maskT:
// 32 coalesced 2B loads per tile per wave (lanes = consecutive q), log2e
// pre-folded.  Block remap co-locates mask sharers (16 heads of one (b,qt))
// on one XCD -> maskT L2-resident.
// grid = 512 (2 blocks/CU); block = 256 (4 waves); 1 barrier/tile.
// ---------------------------------------------------------------------------
__global__ __launch_bounds__(256, 2) void attn_kernel(
    const __hip_bfloat16* __restrict__ Qp, const __hip_bfloat16* __restrict__ Kp,
    const __hip_bfloat16* __restrict__ Vt, const __hip_bfloat16* __restrict__ maskT,
    float* __restrict__ out)
{
    __shared__ __attribute__((aligned(16))) __hip_bfloat16 Kl[2][4096];
    __shared__ __attribute__((aligned(16))) __hip_bfloat16 Vl[2][4096];

    const int tid = threadIdx.x;
    const int lane = tid & 63;
    const int wave = tid >> 6;
    const int ln31 = lane & 31;
    const int hi = lane >> 5;

    // mask-sharing XCD remap: hw = (g%8) + 8h + 128(g/8), g = qt*2+b
    const int hw = blockIdx.x;
    const int x = hw & 127;
    const int h = x >> 3;
    const int g = ((hw >> 7) << 3) + (x & 7);
    const int qt = g >> 1;
    const int b = g & 1;
    const int bh = b * 16 + h;

    const __hip_bfloat16* Qb = Qp + (size_t)bh * SS * DD;
    const __hip_bfloat16* Kb = Kp + (size_t)bh * SS * DD;
    const __hip_bfloat16* Vtb = Vt + (size_t)bh * DD * SS;

    const int q0 = qt * 128 + wave * 32;
    // lane's maskT column: q = q0 + ln31; row stride = SS elements (t-major)
    const __hip_bfloat16* mtb = maskT + (size_t)b * SS * SS + q0 + ln31;

    const int srow = lane >> 3;
    const int scol = ((lane & 7) ^ srow) * 8;
    const int rswz = (lane & 7) << 4;

    bf16x8 qf[4];
    {
        const __hip_bfloat16* qptr = Qb + (size_t)(q0 + ln31) * DD + hi * 8;
#pragma unroll
        for (int kc = 0; kc < 4; ++kc)
            qf[kc] = *reinterpret_cast<const bf16x8*>(qptr + kc * 16);
    }

    bf16x8 ones;
#pragma unroll
    for (int i = 0; i < 8; ++i) ones[i] = (__bf16)1.0f;

    f32x16 o[2];
    f32x16 lacc;
    float m_r = -1e30f;
#pragma unroll
    for (int r = 0; r < 16; ++r) { o[0][r] = 0.f; o[1][r] = 0.f; lacc[r] = 0.f; }

#define STAGE(bufi, t0s)                                                        \
    {                                                                           \
        _Pragma("unroll")                                                       \
        for (int cc = 0; cc < 2; ++cc) {                                        \
            const int c = wave * 2 + cc;                                        \
            const int row = c * 8 + srow;                                       \
            gld16(Kb + (size_t)((t0s) + row) * DD + scol, &Kl[bufi][c * 512]);  \
            gld16(Vtb + (size_t)row * SS + (t0s) + scol, &Vl[bufi][c * 512]);   \
        }                                                                       \
    }

#define KFRAG(nt, kc) (*(const bf16x8*)((const char*)Kl[buf] +                  \
        (nt) * 4096 + ln31 * 128 + (((kc) * 32 + hi * 16) ^ rswz)))
#define VFRAG(dblk, kc) (*(const bf16x8*)((const char*)Vl[buf] +                \
        (dblk) * 4096 + ln31 * 128 + (((kc) * 32 + hi * 16) ^ rswz)))

    STAGE(0, 0);
    __syncthreads();

    int buf = 0;
    for (int t0 = 0; t0 < SS; t0 += 64) {
        const bool has_next = (t0 + 64 < SS);

        // ---- mask C-init: coalesced bf16 loads (already *log2e) ----
        f32x16 s[2];
#pragma unroll
        for (int nt = 0; nt < 2; ++nt)
#pragma unroll
            for (int r = 0; r < 16; ++r) {
                const int t = t0 + nt * 32 + (r & 3) + 8 * (r >> 2) + 4 * hi;
                const unsigned u = *(const unsigned short*)(mtb + (size_t)t * SS);
                s[nt][r] = __uint_as_float(u << 16);
            }

        if (has_next) STAGE(buf ^ 1, t0 + 64);

        // ---- QK^T (swapped): C col=q(ln31), row=t=nt*32+(r&3)+8(r>>2)+4hi ----
        __builtin_amdgcn_s_setprio(1);
#pragma unroll
        for (int kc = 0; kc < 4; ++kc) {
            bf16x8 k0 = KFRAG(0, kc);
            bf16x8 k1 = KFRAG(1, kc);
            s[0] = __builtin_amdgcn_mfma_f32_32x32x16_bf16(k0, qf[kc], s[0], 0, 0, 0);
            s[1] = __builtin_amdgcn_mfma_f32_32x32x16_bf16(k1, qf[kc], s[1], 0, 0, 0);
        }
        __builtin_amdgcn_s_setprio(0);

        // ---- V fragments: issue DS reads now, hide under softmax ----
        bf16x8 vfr[2][4];
#pragma unroll
        for (int dblk = 0; dblk < 2; ++dblk)
#pragma unroll
            for (int kc = 0; kc < 4; ++kc)
                vfr[dblk][kc] = VFRAG(dblk, kc);

        // ---- defer-max: lane-local max over 32 vals + wave vote ----
        float pmax = fmaxf(s[0][0], fmaxf(s[0][1], s[0][2]));
#pragma unroll
        for (int r = 3; r < 16; r += 3)
            pmax = fmaxf(pmax, fmaxf(s[0][r], fmaxf(s[0][(r + 1) & 15], s[0][(r + 2) & 15])));
#pragma unroll
        for (int r = 0; r < 16; r += 4)
            pmax = fmaxf(pmax, fmaxf(fmaxf(s[1][r], s[1][r + 1]), fmaxf(s[1][r + 2], s[1][r + 3])));

        if (!__all(pmax - m_r <= 11.5f)) {
            // slow path (rare): full row-max (half-exchange) + rescale state
            float mx = fmaxf(pmax, __shfl_xor(pmax, 32));
            const float mn = fmaxf(m_r, mx);
            const float alpha = exp2f(m_r - mn);
            m_r = mn;
#pragma unroll
            for (int r = 0; r < 16; ++r) {
                const float a = __shfl(alpha, (r & 3) + 8 * (r >> 2) + 4 * hi);
                o[0][r] *= a; o[1][r] *= a; lacc[r] *= a;
            }
        }

        // ---- P = exp2(s - m) in place ----
#pragma unroll
        for (int nt = 0; nt < 2; ++nt)
#pragma unroll
            for (int r = 0; r < 16; ++r)
                s[nt][r] = __builtin_amdgcn_exp2f(s[nt][r] - m_r);

        // ---- P -> PV A-fragments in-register (one shfl_xor(32) per pair) ----
        bf16x8 pfa[4];
#pragma unroll
        for (int nt = 0; nt < 2; ++nt) {
            unsigned c[8];
#pragma unroll
            for (int j = 0; j < 8; ++j) {
                union { __hip_bfloat162 hh; unsigned u; } cu;
                cu.hh = __float22bfloat162_rn(make_float2(s[nt][2 * j], s[nt][2 * j + 1]));
                c[j] = cu.u;
            }
#pragma unroll
            for (int half = 0; half < 2; ++half) {
                const unsigned c0 = c[half * 4 + 0], c1 = c[half * 4 + 1];
                const unsigned c2 = c[half * 4 + 2], c3 = c[half * 4 + 3];
                const unsigned X  = hi ? c0 : c2;
                const unsigned Y  = (unsigned)__shfl_xor((int)X, 32);
                const unsigned X2 = hi ? c1 : c3;
                const unsigned Y2 = (unsigned)__shfl_xor((int)X2, 32);
                union { bf16x8 v; unsigned w[4]; } pu;
                pu.w[0] = hi ? Y : c0;
                pu.w[1] = hi ? Y2 : c1;
                pu.w[2] = hi ? c2 : Y;
                pu.w[3] = hi ? c3 : Y2;
                pfa[nt * 2 + half] = pu.v;
            }
        }

        // ---- O += P @ V ; l += P @ ones.  C: col=d(ln31), row=q ----
        __builtin_amdgcn_s_setprio(1);
#pragma unroll
        for (int kc = 0; kc < 4; ++kc) {
            lacc = __builtin_amdgcn_mfma_f32_32x32x16_bf16(pfa[kc], ones, lacc, 0, 0, 0);
            o[0] = __builtin_amdgcn_mfma_f32_32x32x16_bf16(pfa[kc], vfr[0][kc], o[0], 0, 0, 0);
            o[1] = __builtin_amdgcn_mfma_f32_32x32x16_bf16(pfa[kc], vfr[1][kc], o[1], 0, 0, 0);
        }
        __builtin_amdgcn_s_setprio(0);

        __syncthreads();
        buf ^= 1;
    }

    // ---- epilogue: normalize and store [B,H,S,D] f32 (coalesced over d) ----
#pragma unroll
    for (int r = 0; r < 16; ++r) {
        const float inv_l = 1.0f / lacc[r];
        const int q = q0 + (r & 3) + 8 * (r >> 2) + 4 * hi;
        float* orow = out + ((size_t)bh * SS + q) * DD + ln31;
        orow[0]  = o[0][r] * inv_l;
        orow[32] = o[1][r] * inv_l;
    }
#undef STAGE
#undef KFRAG
#undef VFRAG
}

extern "C" void kernel_launch(void* const* d_in, const int* in_sizes, int n_in,
                              void* d_out, int out_size, void* d_ws, size_t ws_size,
                              hipStream_t stream) {
    const float* xq        = (const float*)d_in[0];
    const float* xk        = (const float*)d_in[1];
    const float* xv        = (const float*)d_in[2];
    const float* mask      = (const float*)d_in[3];
    const float* inv_scale = (const float*)d_in[4];
    const float* Wq        = (const float*)d_in[5];
    const float* bq        = (const float*)d_in[6];
    const float* Wk        = (const float*)d_in[7];
    const float* bk        = (const float*)d_in[8];
    const float* Wv        = (const float*)d_in[9];
    const float* bv        = (const float*)d_in[10];

    __hip_bfloat16* Qp = (__hip_bfloat16*)d_ws;
    __hip_bfloat16* Kp = Qp + (size_t)BB * HH * SS * DD;
    __hip_bfloat16* Vt = Kp + (size_t)BB * HH * SS * DD;
    __hip_bfloat16* maskT = Vt + (size_t)BB * HH * SS * DD;  // 16.8 MB bf16
    float* out = (float*)d_out;

    maskt_kernel<<<dim3(BB * 32 * 32), dim3(256), 0, stream>>>(mask, maskT);

    proj_kernel<<<dim3(BB * HH, SS / 64), dim3(256), 0, stream>>>(
        xq, xk, xv, Wq, bq, Wk, bk, Wv, bv, inv_scale, Qp, Kp, Vt);

    attn_kernel<<<dim3(512), dim3(256), 0, stream>>>(
        Qp, Kp, Vt, maskT, out);
}

// Round 16
// 122.396 us; speedup vs baseline: 1.3627x; 1.1441x over previous
//
#include <hip/hip_runtime.h>
#include <hip/hip_bf16.h>

#define BB 2
#define SS 2048
#define HH 16
#define DD 64

#define LOG2E 1.4426950408889634f

typedef __bf16 bf16x8 __attribute__((ext_vector_type(8)));
typedef float f32x4 __attribute__((ext_vector_type(4)));
typedef float f32x16 __attribute__((ext_vector_type(16)));

__device__ __forceinline__ void gld16(const __hip_bfloat16* g, __hip_bfloat16* l) {
    __builtin_amdgcn_global_load_lds(
        (const __attribute__((address_space(1))) unsigned int*)g,
        (__attribute__((address_space(3))) unsigned int*)l, 16, 0, 0);
}

// ---------------------------------------------------------------------------
// Kernel 1: fused Q/K/V projection + V transpose + Q pre-scaling. (unchanged)
// ---------------------------------------------------------------------------
__global__ __launch_bounds__(256) void proj_kernel(
    const float* __restrict__ xq, const float* __restrict__ xk,
    const float* __restrict__ xv,
    const float* __restrict__ Wq, const float* __restrict__ bq,
    const float* __restrict__ Wk, const float* __restrict__ bk,
    const float* __restrict__ Wv, const float* __restrict__ bv,
    const float* __restrict__ inv_scale_p,
    __hip_bfloat16* __restrict__ Qp, __hip_bfloat16* __restrict__ Kp,
    __hip_bfloat16* __restrict__ Vt)
{
    __shared__ float w_lds[64][65];
    __shared__ __attribute__((aligned(16))) float x_lds[64][72];
    __shared__ __attribute__((aligned(16))) __hip_bfloat16 vt_lds[64][72];

    const int tid = threadIdx.x;
    const int bh = blockIdx.x;
    const int b = bh >> 4, h = bh & 15;
    const int s0 = blockIdx.y * 64;
    const int e = tid & 63;
    const int rg = tid >> 6;
    const float qscale = LOG2E / inv_scale_p[0];

    const float* xs[3] = {xq, xk, xv};
    const float* Ws[3] = {Wq, Wk, Wv};
    const float* Bs[3] = {bq, bk, bv};

#pragma unroll
    for (int m = 0; m < 3; ++m) {
        __syncthreads();
#pragma unroll
        for (int k = 0; k < 16; ++k) {
            const int i = tid + k * 256;
            w_lds[i & 63][i >> 6] = Ws[m][i];
        }
        {
            const int row = tid >> 2, f0 = tid & 3;
            const float* xrow = xs[m] + ((size_t)((b * SS + s0 + row) * HH + h)) * DD;
            float4* dst = (float4*)&x_lds[row][0];
            const float4* src = (const float4*)xrow;
#pragma unroll
            for (int j = 0; j < 4; ++j) dst[f0 + 4 * j] = src[f0 + 4 * j];
        }
        const float bias_e = Bs[m][e];
        __syncthreads();

        float acc[16];
#pragma unroll
        for (int it = 0; it < 16; ++it) acc[it] = bias_e;
#pragma unroll
        for (int dq = 0; dq < 16; ++dq) {
            const float w0 = w_lds[dq * 4 + 0][e];
            const float w1 = w_lds[dq * 4 + 1][e];
            const float w2 = w_lds[dq * 4 + 2][e];
            const float w3 = w_lds[dq * 4 + 3][e];
#pragma unroll
            for (int it = 0; it < 16; ++it) {
                const float4 x4 = *(const float4*)&x_lds[rg * 16 + it][dq * 4];
                acc[it] = fmaf(x4.x, w0, fmaf(x4.y, w1, fmaf(x4.z, w2, fmaf(x4.w, w3, acc[it]))));
            }
        }

        if (m == 0) {
#pragma unroll
            for (int it = 0; it < 16; ++it)
                Qp[((size_t)bh * SS + s0 + rg * 16 + it) * DD + e] =
                    __float2bfloat16(acc[it] * qscale);
        } else if (m == 1) {
#pragma unroll
            for (int it = 0; it < 16; ++it)
                Kp[((size_t)bh * SS + s0 + rg * 16 + it) * DD + e] =
                    __float2bfloat16(acc[it]);
        } else {
#pragma unroll
            for (int it = 0; it < 16; ++it)
                vt_lds[e][rg * 16 + it] = __float2bfloat16(acc[it]);
            __syncthreads();
            const int row2 = tid >> 2, f = tid & 3;
            bf16x8 vv0 = *(const bf16x8*)&vt_lds[row2][f * 16];
            bf16x8 vv1 = *(const bf16x8*)&vt_lds[row2][f * 16 + 8];
            __hip_bfloat16* dst = &Vt[((size_t)bh * DD + row2) * SS + s0 + f * 16];
            *(bf16x8*)dst = vv0;
            *(bf16x8*)(dst + 8) = vv1;
        }
    }
}

// ---------------------------------------------------------------------------
// Kernel 1b: mask transpose + log2e premul + bf16 narrowing. (unchanged)
//   maskT[b][t][q] = bf16(mask[b][q][t] * LOG2E)
// ---------------------------------------------------------------------------
__global__ __launch_bounds__(256) void maskt_kernel(
    const float* __restrict__ mask, __hip_bfloat16* __restrict__ mt)
{
    __shared__ float tl[64][65];
    const int bid = blockIdx.x;
    const int b = bid >> 10;
    const int q64 = (bid >> 5) & 31;
    const int t64 = bid & 31;
    const int tid = threadIdx.x;
    const int r0 = tid >> 4;
    const int c0 = (tid & 15) * 4;

    const float* src = mask + (size_t)b * SS * SS + (size_t)(q64 * 64) * SS + t64 * 64;
#pragma unroll
    for (int p = 0; p < 4; ++p) {
        const int r = p * 16 + r0;
        const float4 v = *(const float4*)&src[(size_t)r * SS + c0];
        tl[r][c0 + 0] = v.x; tl[r][c0 + 1] = v.y;
        tl[r][c0 + 2] = v.z; tl[r][c0 + 3] = v.w;
    }
    __syncthreads();

    __hip_bfloat16* dst = mt + (size_t)b * SS * SS + (size_t)(t64 * 64) * SS + q64 * 64;
#pragma unroll
    for (int p = 0; p < 4; ++p) {
        const int tt = p * 16 + r0;
        union { ushort4 u4; __hip_bfloat16 h[4]; } w;
        w.h[0] = __float2bfloat16(tl[c0 + 0][tt] * LOG2E);
        w.h[1] = __float2bfloat16(tl[c0 + 1][tt] * LOG2E);
        w.h[2] = __float2bfloat16(tl[c0 + 2][tt] * LOG2E);
        w.h[3] = __float2bfloat16(tl[c0 + 3][tt] * LOG2E);
        *(ushort4*)&dst[(size_t)tt * SS + c0] = w.u4;
    }
}

// ---------------------------------------------------------------------------
// Kernel 2: flash attention.  K/V AND maskT tiles staged via global_load_lds
// (double-buffered).  Mask C-init = 32x ds_read_u16 with immediate offsets
// (zero address VALU).  V fragments loaded after softmax (less reg pressure).
// 32x32x16 MFMA, 32 q-rows/wave, QBLK=128.
// grid = 512 (2 blocks/CU); block = 256 (4 waves); 1 barrier/tile.
// ---------------------------------------------------------------------------
__global__ __launch_bounds__(256, 2) void attn_kernel(
    const __hip_bfloat16* __restrict__ Qp, const __hip_bfloat16* __restrict__ Kp,
    const __hip_bfloat16* __restrict__ Vt, const __hip_bfloat16* __restrict__ maskT,
    float* __restrict__ out)
{
    __shared__ __attribute__((aligned(16))) __hip_bfloat16 Kl[2][4096];
    __shared__ __attribute__((aligned(16))) __hip_bfloat16 Vl[2][4096];
    __shared__ __attribute__((aligned(16))) __hip_bfloat16 Ml[2][8192]; // [t:64][q:128]

    const int tid = threadIdx.x;
    const int lane = tid & 63;
    const int wave = tid >> 6;
    const int ln31 = lane & 31;
    const int hi = lane >> 5;

    // mask-sharing XCD remap: hw = (g%8) + 8h + 128(g/8), g = qt*2+b
    const int hw = blockIdx.x;
    const int x = hw & 127;
    const int h = x >> 3;
    const int g = ((hw >> 7) << 3) + (x & 7);
    const int qt = g >> 1;
    const int b = g & 1;
    const int bh = b * 16 + h;

    const __hip_bfloat16* Qb = Qp + (size_t)bh * SS * DD;
    const __hip_bfloat16* Kb = Kp + (size_t)bh * SS * DD;
    const __hip_bfloat16* Vtb = Vt + (size_t)bh * DD * SS;
    const __hip_bfloat16* Mtb = maskT + (size_t)b * SS * SS + qt * 128; // row t: + t*SS

    const int q0 = qt * 128 + wave * 32;

    const int srow = lane >> 3;
    const int scol = ((lane & 7) ^ srow) * 8;
    const int rswz = (lane & 7) << 4;
    // M staging: call c covers rows 4c..4c+3; lane -> (row = 4c + lane>>4, qoff = (lane&15)*8)
    const int mrow = lane >> 4;
    const int mqoff = (lane & 15) * 8;
    // M read base (bytes): column q = wave*32 + ln31, half hi -> +hi*1024
    const int mrbase = ln31 * 2 + wave * 64 + hi * 1024;

    bf16x8 qf[4];
    {
        const __hip_bfloat16* qptr = Qb + (size_t)(q0 + ln31) * DD + hi * 8;
#pragma unroll
        for (int kc = 0; kc < 4; ++kc)
            qf[kc] = *reinterpret_cast<const bf16x8*>(qptr + kc * 16);
    }

    bf16x8 ones;
#pragma unroll
    for (int i = 0; i < 8; ++i) ones[i] = (__bf16)1.0f;

    f32x16 o[2];
    f32x16 lacc;
    float m_r = -1e30f;
#pragma unroll
    for (int r = 0; r < 16; ++r) { o[0][r] = 0.f; o[1][r] = 0.f; lacc[r] = 0.f; }

#define STAGE(bufi, t0s)                                                        \
    {                                                                           \
        _Pragma("unroll")                                                       \
        for (int cc = 0; cc < 2; ++cc) {                                        \
            const int c = wave * 2 + cc;                                        \
            const int row = c * 8 + srow;                                       \
            gld16(Kb + (size_t)((t0s) + row) * DD + scol, &Kl[bufi][c * 512]);  \
            gld16(Vtb + (size_t)row * SS + (t0s) + scol, &Vl[bufi][c * 512]);   \
        }                                                                       \
        _Pragma("unroll")                                                       \
        for (int cc = 0; cc < 4; ++cc) {                                        \
            const int c = wave * 4 + cc;                                        \
            const int row = c * 4 + mrow;                                       \
            gld16(Mtb + (size_t)((t0s) + row) * SS + mqoff, &Ml[bufi][c * 512]);\
        }                                                                       \
    }

#define KFRAG(nt, kc) (*(const bf16x8*)((const char*)Kl[buf] +                  \
        (nt) * 4096 + ln31 * 128 + (((kc) * 32 + hi * 16) ^ rswz)))
#define VFRAG(dblk, kc) (*(const bf16x8*)((const char*)Vl[buf] +                \
        (dblk) * 4096 + ln31 * 128 + (((kc) * 32 + hi * 16) ^ rswz)))

    STAGE(0, 0);
    __syncthreads();

    int buf = 0;
    for (int t0 = 0; t0 < SS; t0 += 64) {
        const bool has_next = (t0 + 64 < SS);

        // ---- mask C-init from LDS: immediate-offset u16 reads ----
        f32x16 s[2];
#pragma unroll
        for (int nt = 0; nt < 2; ++nt)
#pragma unroll
            for (int r = 0; r < 16; ++r) {
                // byte offset: mrbase + (nt*32 + (r&3) + 8*(r>>2)) * 256  (constant part)
                const unsigned u = *(const unsigned short*)((const char*)Ml[buf] +
                    mrbase + (nt * 32 + (r & 3) + 8 * (r >> 2)) * 256);
                s[nt][r] = __uint_as_float(u << 16);
            }

        if (has_next) STAGE(buf ^ 1, t0 + 64);

        // ---- QK^T (swapped): C col=q(ln31), row=t=nt*32+(r&3)+8(r>>2)+4hi ----
        __builtin_amdgcn_s_setprio(1);
#pragma unroll
        for (int kc = 0; kc < 4; ++kc) {
            bf16x8 k0 = KFRAG(0, kc);
            bf16x8 k1 = KFRAG(1, kc);
            s[0] = __builtin_amdgcn_mfma_f32_32x32x16_bf16(k0, qf[kc], s[0], 0, 0, 0);
            s[1] = __builtin_amdgcn_mfma_f32_32x32x16_bf16(k1, qf[kc], s[1], 0, 0, 0);
        }
        __builtin_amdgcn_s_setprio(0);

        // ---- defer-max: lane-local max over 32 vals + wave vote ----
        float pmax = fmaxf(s[0][0], fmaxf(s[0][1], s[0][2]));
#pragma unroll
        for (int r = 3; r < 16; r += 3)
            pmax = fmaxf(pmax, fmaxf(s[0][r], fmaxf(s[0][(r + 1) & 15], s[0][(r + 2) & 15])));
#pragma unroll
        for (int r = 0; r < 16; r += 4)
            pmax = fmaxf(pmax, fmaxf(fmaxf(s[1][r], s[1][r + 1]), fmaxf(s[1][r + 2], s[1][r + 3])));

        if (!__all(pmax - m_r <= 11.5f)) {
            // slow path (rare): full row-max (half-exchange) + rescale state
            float mx = fmaxf(pmax, __shfl_xor(pmax, 32));
            const float mn = fmaxf(m_r, mx);
            const float alpha = exp2f(m_r - mn);
            m_r = mn;
#pragma unroll
            for (int r = 0; r < 16; ++r) {
                const float a = __shfl(alpha, (r & 3) + 8 * (r >> 2) + 4 * hi);
                o[0][r] *= a; o[1][r] *= a; lacc[r] *= a;
            }
        }

        // ---- P = exp2(s - m) in place ----
#pragma unroll
        for (int nt = 0; nt < 2; ++nt)
#pragma unroll
            for (int r = 0; r < 16; ++r)
                s[nt][r] = __builtin_amdgcn_exp2f(s[nt][r] - m_r);

        // ---- V fragments (issued here: shorter live range) ----
        bf16x8 vfr[2][4];
#pragma unroll
        for (int dblk = 0; dblk < 2; ++dblk)
#pragma unroll
            for (int kc = 0; kc < 4; ++kc)
                vfr[dblk][kc] = VFRAG(dblk, kc);

        // ---- P -> PV A-fragments in-register (one shfl_xor(32) per pair) ----
        bf16x8 pfa[4];
#pragma unroll
        for (int nt = 0; nt < 2; ++nt) {
            unsigned c[8];
#pragma unroll
            for (int j = 0; j < 8; ++j) {
                union { __hip_bfloat162 hh; unsigned u; } cu;
                cu.hh = __float22bfloat162_rn(make_float2(s[nt][2 * j], s[nt][2 * j + 1]));
                c[j] = cu.u;
            }
#pragma unroll
            for (int half = 0; half < 2; ++half) {
                const unsigned c0 = c[half * 4 + 0], c1 = c[half * 4 + 1];
                const unsigned c2 = c[half * 4 + 2], c3 = c[half * 4 + 3];
                const unsigned X  = hi ? c0 : c2;
                const unsigned Y  = (unsigned)__shfl_xor((int)X, 32);
                const unsigned X2 = hi ? c1 : c3;
                const unsigned Y2 = (unsigned)__shfl_xor((int)X2, 32);
                union { bf16x8 v; unsigned w[4]; } pu;
                pu.w[0] = hi ? Y : c0;
                pu.w[1] = hi ? Y2 : c1;
                pu.w[2] = hi ? c2 : Y;
                pu.w[3] = hi ? c3 : Y2;
                pfa[nt * 2 + half] = pu.v;
            }
        }

        // ---- O += P @ V ; l += P @ ones.  C: col=d(ln31), row=q ----
        __builtin_amdgcn_s_setprio(1);
#pragma unroll
        for (int kc = 0; kc < 4; ++kc) {
            lacc = __builtin_amdgcn_mfma_f32_32x32x16_bf16(pfa[kc], ones, lacc, 0, 0, 0);
            o[0] = __builtin_amdgcn_mfma_f32_32x32x16_bf16(pfa[kc], vfr[0][kc], o[0], 0, 0, 0);
            o[1] = __builtin_amdgcn_mfma_f32_32x32x16_bf16(pfa[kc], vfr[1][kc], o[1], 0, 0, 0);
        }
        __builtin_amdgcn_s_setprio(0);

        __syncthreads();
        buf ^= 1;
    }

    // ---- epilogue: normalize and store [B,H,S,D] f32 (coalesced over d) ----
#pragma unroll
    for (int r = 0; r < 16; ++r) {
        const float inv_l = 1.0f / lacc[r];
        const int q = q0 + (r & 3) + 8 * (r >> 2) + 4 * hi;
        float* orow = out + ((size_t)bh * SS + q) * DD + ln31;
        orow[0]  = o[0][r] * inv_l;
        orow[32] = o[1][r] * inv_l;
    }
#undef STAGE
#undef KFRAG
#undef VFRAG
}

extern "C" void kernel_launch(void* const* d_in, const int* in_sizes, int n_in,
                              void* d_out, int out_size, void* d_ws, size_t ws_size,
                              hipStream_t stream) {
    const float* xq        = (const float*)d_in[0];
    const float* xk        = (const float*)d_in[1];
    const float* xv        = (const float*)d_in[2];
    const float* mask      = (const float*)d_in[3];
    const float* inv_scale = (const float*)d_in[4];
    const float* Wq        = (const float*)d_in[5];
    const float* bq        = (const float*)d_in[6];
    const float* Wk        = (const float*)d_in[7];
    const float* bk        = (const float*)d_in[8];
    const float* Wv        = (const float*)d_in[9];
    const float* bv        = (const float*)d_in[10];

    __hip_bfloat16* Qp = (__hip_bfloat16*)d_ws;
    __hip_bfloat16* Kp = Qp + (size_t)BB * HH * SS * DD;
    __hip_bfloat16* Vt = Kp + (size_t)BB * HH * SS * DD;
    __hip_bfloat16* maskT = Vt + (size_t)BB * HH * SS * DD;  // 16.8 MB bf16
    float* out = (float*)d_out;

    maskt_kernel<<<dim3(BB * 32 * 32), dim3(256), 0, stream>>>(mask, maskT);

    proj_kernel<<<dim3(BB * HH, SS / 64), dim3(256), 0, stream>>>(
        xq, xk, xv, Wq, bq, Wk, bk, Wv, bv, inv_scale, Qp, Kp, Vt);

    attn_kernel<<<dim3(512), dim3(256), 0, stream>>>(
        Qp, Kp, Vt, maskT, out);
}

// Round 17
// 98.409 us; speedup vs baseline: 1.6948x; 1.2438x over previous
//
#include <hip/hip_runtime.h>
#include <hip/hip_bf16.h>

#define BB 2
#define SS 2048
#define HH 16
#define DD 64

#define LOG2E 1.4426950408889634f

typedef __bf16 bf16x8 __attribute__((ext_vector_type(8)));
typedef float f32x4 __attribute__((ext_vector_type(4)));
typedef float f32x16 __attribute__((ext_vector_type(16)));

__device__ __forceinline__ void gld16(const __hip_bfloat16* g, __hip_bfloat16* l) {
    __builtin_amdgcn_global_load_lds(
        (const __attribute__((address_space(1))) unsigned int*)g,
        (__attribute__((address_space(3))) unsigned int*)l, 16, 0, 0);
}

// split 8 f32 into bf16 hi + bf16 residual (error-free 3-term MFMA scheme)
__device__ __forceinline__ void split8(const float* v, bf16x8& h8, bf16x8& l8) {
#pragma unroll
    for (int i = 0; i < 8; ++i) {
        const float x = v[i];
        const __bf16 hb = (__bf16)x;
        h8[i] = hb;
        l8[i] = (__bf16)(x - (float)hb);
    }
}

// ---------------------------------------------------------------------------
// Kernel 1: MFMA-based Q/K/V projection + V transpose + Q pre-scaling.
// out[s][e] = sum_d x[s][d] W[e][d] + b[e]   (3-term bf16 split, fp32 accum)
// grid = (B*H, S/128); block = 128 (2 waves, 64 s-rows each); no barriers.
//   Q, K -> [B,H,S,D] bf16 (Q pre-multiplied by log2e/inv_scale)
//   V    -> Vt [B,H,D,S] bf16
// ---------------------------------------------------------------------------
__global__ __launch_bounds__(128) void proj_kernel(
    const float* __restrict__ xq, const float* __restrict__ xk,
    const float* __restrict__ xv,
    const float* __restrict__ Wq, const float* __restrict__ bq,
    const float* __restrict__ Wk, const float* __restrict__ bk,
    const float* __restrict__ Wv, const float* __restrict__ bv,
    const float* __restrict__ inv_scale_p,
    __hip_bfloat16* __restrict__ Qp, __hip_bfloat16* __restrict__ Kp,
    __hip_bfloat16* __restrict__ Vt)
{
    __shared__ __attribute__((aligned(16))) __hip_bfloat16 tl[2][64][72];

    const int tid = threadIdx.x;
    const int wave = tid >> 6;
    const int lane = tid & 63;
    const int ln31 = lane & 31;
    const int hi = lane >> 5;
    const int bh = blockIdx.x;
    const int b = bh >> 4, h = bh & 15;
    const int s0 = blockIdx.y * 128 + wave * 64;    // wave owns rows s0..s0+63
    const float qscale = LOG2E / inv_scale_p[0];

    const float* xs[3] = {xq, xk, xv};
    const float* Ws[3] = {Wq, Wk, Wv};
    const float* Bs[3] = {bq, bk, bv};

#pragma unroll
    for (int m = 0; m < 3; ++m) {
        // ---- W fragments: B-operand, col e = Nb*32+ln31, k = kc*16+hi*8+i ----
        bf16x8 wh[2][4], wl[2][4];
        float biasv[2];
#pragma unroll
        for (int Nb = 0; Nb < 2; ++Nb) {
            const int e = Nb * 32 + ln31;
            biasv[Nb] = Bs[m][e];
            const float* wr = Ws[m] + e * 64 + hi * 8;
#pragma unroll
            for (int kc = 0; kc < 4; ++kc) {
                float v[8];
                const float4 a = *(const float4*)(wr + kc * 16);
                const float4 c = *(const float4*)(wr + kc * 16 + 4);
                v[0] = a.x; v[1] = a.y; v[2] = a.z; v[3] = a.w;
                v[4] = c.x; v[5] = c.y; v[6] = c.z; v[7] = c.w;
                split8(v, wh[Nb][kc], wl[Nb][kc]);
            }
        }
        const float scale = (m == 0) ? qscale : 1.0f;

#pragma unroll
        for (int Mb = 0; Mb < 2; ++Mb) {
            // ---- x fragments: A-operand, row s = s0+Mb*32+ln31 ----
            const int s = s0 + Mb * 32 + ln31;
            const float* xr = xs[m] + ((size_t)(b * SS + s) * HH + h) * DD + hi * 8;
            bf16x8 xh[4], xl[4];
#pragma unroll
            for (int kc = 0; kc < 4; ++kc) {
                float v[8];
                const float4 a = *(const float4*)(xr + kc * 16);
                const float4 c = *(const float4*)(xr + kc * 16 + 4);
                v[0] = a.x; v[1] = a.y; v[2] = a.z; v[3] = a.w;
                v[4] = c.x; v[5] = c.y; v[6] = c.z; v[7] = c.w;
                split8(v, xh[kc], xl[kc]);
            }

            // ---- acc[Nb]: C col = e (ln31), row = Mb*32+(r&3)+8(r>>2)+4hi ----
            f32x16 acc[2];
#pragma unroll
            for (int Nb = 0; Nb < 2; ++Nb)
#pragma unroll
                for (int r = 0; r < 16; ++r) acc[Nb][r] = biasv[Nb];

#pragma unroll
            for (int Nb = 0; Nb < 2; ++Nb)
#pragma unroll
                for (int kc = 0; kc < 4; ++kc) {
                    acc[Nb] = __builtin_amdgcn_mfma_f32_32x32x16_bf16(xh[kc], wh[Nb][kc], acc[Nb], 0, 0, 0);
                    acc[Nb] = __builtin_amdgcn_mfma_f32_32x32x16_bf16(xl[kc], wh[Nb][kc], acc[Nb], 0, 0, 0);
                    acc[Nb] = __builtin_amdgcn_mfma_f32_32x32x16_bf16(xh[kc], wl[Nb][kc], acc[Nb], 0, 0, 0);
                }

            // ---- write to wave-private LDS tile ----
            if (m < 2) {
#pragma unroll
                for (int Nb = 0; Nb < 2; ++Nb)
#pragma unroll
                    for (int r = 0; r < 16; ++r) {
                        const int row = Mb * 32 + (r & 3) + 8 * (r >> 2) + 4 * hi;
                        tl[wave][row][Nb * 32 + ln31] =
                            __float2bfloat16(acc[Nb][r] * scale);
                    }
            } else {
#pragma unroll
                for (int Nb = 0; Nb < 2; ++Nb)
#pragma unroll
                    for (int r = 0; r < 16; ++r) {
                        const int srow = Mb * 32 + (r & 3) + 8 * (r >> 2) + 4 * hi;
                        tl[wave][Nb * 32 + ln31][srow] = __float2bfloat16(acc[Nb][r]);
                    }
            }
        }

        // ---- coalesced store from LDS (wave-private; lgkmcnt ordering) ----
        if (m < 2) {
            __hip_bfloat16* outp = (m == 0 ? Qp : Kp) + ((size_t)bh * SS + s0) * DD;
#pragma unroll
            for (int j = 0; j < 8; ++j) {
                const int row = j * 8 + (lane >> 3);
                const int col = (lane & 7) * 8;
                bf16x8 v = *(const bf16x8*)&tl[wave][row][col];
                *(bf16x8*)(outp + row * 64 + col) = v;
            }
        } else {
            __hip_bfloat16* vtp = Vt + (size_t)bh * DD * SS + s0;
#pragma unroll
            for (int j = 0; j < 8; ++j) {
                const int d = j * 8 + (lane >> 3);
                const int scol = (lane & 7) * 8;
                bf16x8 v = *(const bf16x8*)&tl[wave][d][scol];
                *(bf16x8*)(vtp + (size_t)d * SS + scol) = v;
            }
        }
    }
}

// ---------------------------------------------------------------------------
// Kernel 1b: mask transpose + log2e premul + bf16 narrowing. (unchanged)
//   maskT[b][t][q] = bf16(mask[b][q][t] * LOG2E)
// ---------------------------------------------------------------------------
__global__ __launch_bounds__(256) void maskt_kernel(
    const float* __restrict__ mask, __hip_bfloat16* __restrict__ mt)
{
    __shared__ float tl[64][65];
    const int bid = blockIdx.x;
    const int b = bid >> 10;
    const int q64 = (bid >> 5) & 31;
    const int t64 = bid & 31;
    const int tid = threadIdx.x;
    const int r0 = tid >> 4;
    const int c0 = (tid & 15) * 4;

    const float* src = mask + (size_t)b * SS * SS + (size_t)(q64 * 64) * SS + t64 * 64;
#pragma unroll
    for (int p = 0; p < 4; ++p) {
        const int r = p * 16 + r0;
        const float4 v = *(const float4*)&src[(size_t)r * SS + c0];
        tl[r][c0 + 0] = v.x; tl[r][c0 + 1] = v.y;
        tl[r][c0 + 2] = v.z; tl[r][c0 + 3] = v.w;
    }
    __syncthreads();

    __hip_bfloat16* dst = mt + (size_t)b * SS * SS + (size_t)(t64 * 64) * SS + q64 * 64;
#pragma unroll
    for (int p = 0; p < 4; ++p) {
        const int tt = p * 16 + r0;
        union { ushort4 u4; __hip_bfloat16 h[4]; } w;
        w.h[0] = __float2bfloat16(tl[c0 + 0][tt] * LOG2E);
        w.h[1] = __float2bfloat16(tl[c0 + 1][tt] * LOG2E);
        w.h[2] = __float2bfloat16(tl[c0 + 2][tt] * LOG2E);
        w.h[3] = __float2bfloat16(tl[c0 + 3][tt] * LOG2E);
        *(ushort4*)&dst[(size_t)tt * SS + c0] = w.u4;
    }
}

// ---------------------------------------------------------------------------
// Kernel 2: flash attention. (unchanged from round 16 — K/V + maskT staged
// via global_load_lds dbuf; mask C-init = immediate-offset ds_read_u16.)
// ---------------------------------------------------------------------------
__global__ __launch_bounds__(256, 2) void attn_kernel(
    const __hip_bfloat16* __restrict__ Qp, const __hip_bfloat16* __restrict__ Kp,
    const __hip_bfloat16* __restrict__ Vt, const __hip_bfloat16* __restrict__ maskT,
    float* __restrict__ out)
{
    __shared__ __attribute__((aligned(16))) __hip_bfloat16 Kl[2][4096];
    __shared__ __attribute__((aligned(16))) __hip_bfloat16 Vl[2][4096];
    __shared__ __attribute__((aligned(16))) __hip_bfloat16 Ml[2][8192]; // [t:64][q:128]

    const int tid = threadIdx.x;
    const int lane = tid & 63;
    const int wave = tid >> 6;
    const int ln31 = lane & 31;
    const int hi = lane >> 5;

    // mask-sharing XCD remap: hw = (g%8) + 8h + 128(g/8), g = qt*2+b
    const int hw = blockIdx.x;
    const int x = hw & 127;
    const int h = x >> 3;
    const int g = ((hw >> 7) << 3) + (x & 7);
    const int qt = g >> 1;
    const int b = g & 1;
    const int bh = b * 16 + h;

    const __hip_bfloat16* Qb = Qp + (size_t)bh * SS * DD;
    const __hip_bfloat16* Kb = Kp + (size_t)bh * SS * DD;
    const __hip_bfloat16* Vtb = Vt + (size_t)bh * DD * SS;
    const __hip_bfloat16* Mtb = maskT + (size_t)b * SS * SS + qt * 128;

    const int q0 = qt * 128 + wave * 32;

    const int srow = lane >> 3;
    const int scol = ((lane & 7) ^ srow) * 8;
    const int rswz = (lane & 7) << 4;
    const int mrow = lane >> 4;
    const int mqoff = (lane & 15) * 8;
    const int mrbase = ln31 * 2 + wave * 64 + hi * 1024;

    bf16x8 qf[4];
    {
        const __hip_bfloat16* qptr = Qb + (size_t)(q0 + ln31) * DD + hi * 8;
#pragma unroll
        for (int kc = 0; kc < 4; ++kc)
            qf[kc] = *reinterpret_cast<const bf16x8*>(qptr + kc * 16);
    }

    bf16x8 ones;
#pragma unroll
    for (int i = 0; i < 8; ++i) ones[i] = (__bf16)1.0f;

    f32x16 o[2];
    f32x16 lacc;
    float m_r = -1e30f;
#pragma unroll
    for (int r = 0; r < 16; ++r) { o[0][r] = 0.f; o[1][r] = 0.f; lacc[r] = 0.f; }

#define STAGE(bufi, t0s)                                                        \
    {                                                                           \
        _Pragma("unroll")                                                       \
        for (int cc = 0; cc < 2; ++cc) {                                        \
            const int c = wave * 2 + cc;                                        \
            const int row = c * 8 + srow;                                       \
            gld16(Kb + (size_t)((t0s) + row) * DD + scol, &Kl[bufi][c * 512]);  \
            gld16(Vtb + (size_t)row * SS + (t0s) + scol, &Vl[bufi][c * 512]);   \
        }                                                                       \
        _Pragma("unroll")                                                       \
        for (int cc = 0; cc < 4; ++cc) {                                        \
            const int c = wave * 4 + cc;                                        \
            const int row = c * 4 + mrow;                                       \
            gld16(Mtb + (size_t)((t0s) + row) * SS + mqoff, &Ml[bufi][c * 512]);\
        }                                                                       \
    }

#define KFRAG(nt, kc) (*(const bf16x8*)((const char*)Kl[buf] +                  \
        (nt) * 4096 + ln31 * 128 + (((kc) * 32 + hi * 16) ^ rswz)))
#define VFRAG(dblk, kc) (*(const bf16x8*)((const char*)Vl[buf] +                \
        (dblk) * 4096 + ln31 * 128 + (((kc) * 32 + hi * 16) ^ rswz)))

    STAGE(0, 0);
    __syncthreads();

    int buf = 0;
    for (int t0 = 0; t0 < SS; t0 += 64) {
        const bool has_next = (t0 + 64 < SS);

        // ---- mask C-init from LDS: immediate-offset u16 reads ----
        f32x16 s[2];
#pragma unroll
        for (int nt = 0; nt < 2; ++nt)
#pragma unroll
            for (int r = 0; r < 16; ++r) {
                const unsigned u = *(const unsigned short*)((const char*)Ml[buf] +
                    mrbase + (nt * 32 + (r & 3) + 8 * (r >> 2)) * 256);
                s[nt][r] = __uint_as_float(u << 16);
            }

        if (has_next) STAGE(buf ^ 1, t0 + 64);

        // ---- QK^T (swapped): C col=q(ln31), row=t=nt*32+(r&3)+8(r>>2)+4hi ----
        __builtin_amdgcn_s_setprio(1);
#pragma unroll
        for (int kc = 0; kc < 4; ++kc) {
            bf16x8 k0 = KFRAG(0, kc);
            bf16x8 k1 = KFRAG(1, kc);
            s[0] = __builtin_amdgcn_mfma_f32_32x32x16_bf16(k0, qf[kc], s[0], 0, 0, 0);
            s[1] = __builtin_amdgcn_mfma_f32_32x32x16_bf16(k1, qf[kc], s[1], 0, 0, 0);
        }
        __builtin_amdgcn_s_setprio(0);

        // ---- defer-max: lane-local max over 32 vals + wave vote ----
        float pmax = fmaxf(s[0][0], fmaxf(s[0][1], s[0][2]));
#pragma unroll
        for (int r = 3; r < 16; r += 3)
            pmax = fmaxf(pmax, fmaxf(s[0][r], fmaxf(s[0][(r + 1) & 15], s[0][(r + 2) & 15])));
#pragma unroll
        for (int r = 0; r < 16; r += 4)
            pmax = fmaxf(pmax, fmaxf(fmaxf(s[1][r], s[1][r + 1]), fmaxf(s[1][r + 2], s[1][r + 3])));

        if (!__all(pmax - m_r <= 11.5f)) {
            float mx = fmaxf(pmax, __shfl_xor(pmax, 32));
            const float mn = fmaxf(m_r, mx);
            const float alpha = exp2f(m_r - mn);
            m_r = mn;
#pragma unroll
            for (int r = 0; r < 16; ++r) {
                const float a = __shfl(alpha, (r & 3) + 8 * (r >> 2) + 4 * hi);
                o[0][r] *= a; o[1][r] *= a; lacc[r] *= a;
            }
        }

        // ---- P = exp2(s - m) in place ----
#pragma unroll
        for (int nt = 0; nt < 2; ++nt)
#pragma unroll
            for (int r = 0; r < 16; ++r)
                s[nt][r] = __builtin_amdgcn_exp2f(s[nt][r] - m_r);

        // ---- V fragments ----
        bf16x8 vfr[2][4];
#pragma unroll
        for (int dblk = 0; dblk < 2; ++dblk)
#pragma unroll
            for (int kc = 0; kc < 4; ++kc)
                vfr[dblk][kc] = VFRAG(dblk, kc);

        // ---- P -> PV A-fragments in-register (one shfl_xor(32) per pair) ----
        bf16x8 pfa[4];
#pragma unroll
        for (int nt = 0; nt < 2; ++nt) {
            unsigned c[8];
#pragma unroll
            for (int j = 0; j < 8; ++j) {
                union { __hip_bfloat162 hh; unsigned u; } cu;
                cu.hh = __float22bfloat162_rn(make_float2(s[nt][2 * j], s[nt][2 * j + 1]));
                c[j] = cu.u;
            }
#pragma unroll
            for (int half = 0; half < 2; ++half) {
                const unsigned c0 = c[half * 4 + 0], c1 = c[half * 4 + 1];
                const unsigned c2 = c[half * 4 + 2], c3 = c[half * 4 + 3];
                const unsigned X  = hi ? c0 : c2;
                const unsigned Y  = (unsigned)__shfl_xor((int)X, 32);
                const unsigned X2 = hi ? c1 : c3;
                const unsigned Y2 = (unsigned)__shfl_xor((int)X2, 32);
                union { bf16x8 v; unsigned w[4]; } pu;
                pu.w[0] = hi ? Y : c0;
                pu.w[1] = hi ? Y2 : c1;
                pu.w[2] = hi ? c2 : Y;
                pu.w[3] = hi ? c3 : Y2;
                pfa[nt * 2 + half] = pu.v;
            }
        }

        // ---- O += P @ V ; l += P @ ones ----
        __builtin_amdgcn_s_setprio(1);
#pragma unroll
        for (int kc = 0; kc < 4; ++kc) {
            lacc = __builtin_amdgcn_mfma_f32_32x32x16_bf16(pfa[kc], ones, lacc, 0, 0, 0);
            o[0] = __builtin_amdgcn_mfma_f32_32x32x16_bf16(pfa[kc], vfr[0][kc], o[0], 0, 0, 0);
            o[1] = __builtin_amdgcn_mfma_f32_32x32x16_bf16(pfa[kc], vfr[1][kc], o[1], 0, 0, 0);
        }
        __builtin_amdgcn_s_setprio(0);

        __syncthreads();
        buf ^= 1;
    }

    // ---- epilogue ----
#pragma unroll
    for (int r = 0; r < 16; ++r) {
        const float inv_l = 1.0f / lacc[r];
        const int q = q0 + (r & 3) + 8 * (r >> 2) + 4 * hi;
        float* orow = out + ((size_t)bh * SS + q) * DD + ln31;
        orow[0]  = o[0][r] * inv_l;
        orow[32] = o[1][r] * inv_l;
    }
#undef STAGE
#undef KFRAG
#undef VFRAG
}

extern "C" void kernel_launch(void* const* d_in, const int* in_sizes, int n_in,
                              void* d_out, int out_size, void* d_ws, size_t ws_size,
                              hipStream_t stream) {
    const float* xq        = (const float*)d_in[0];
    const float* xk        = (const float*)d_in[1];
    const float* xv        = (const float*)d_in[2];
    const float* mask      = (const float*)d_in[3];
    const float* inv_scale = (const float*)d_in[4];
    const float* Wq        = (const float*)d_in[5];
    const float* bq        = (const float*)d_in[6];
    const float* Wk        = (const float*)d_in[7];
    const float* bk        = (const float*)d_in[8];
    const float* Wv        = (const float*)d_in[9];
    const float* bv        = (const float*)d_in[10];

    __hip_bfloat16* Qp = (__hip_bfloat16*)d_ws;
    __hip_bfloat16* Kp = Qp + (size_t)BB * HH * SS * DD;
    __hip_bfloat16* Vt = Kp + (size_t)BB * HH * SS * DD;
    __hip_bfloat16* maskT = Vt + (size_t)BB * HH * SS * DD;  // 16.8 MB bf16
    float* out = (float*)d_out;

    maskt_kernel<<<dim3(BB * 32 * 32), dim3(256), 0, stream>>>(mask, maskT);

    proj_kernel<<<dim3(BB * HH, SS / 128), dim3(128), 0, stream>>>(
        xq, xk, xv, Wq, bq, Wk, bk, Wv, bv, inv_scale, Qp, Kp, Vt);

    attn_kernel<<<dim3(512), dim3(256), 0, stream>>>(
        Qp, Kp, Vt, maskT, out);
}